// Round 17
// baseline (176.331 us; speedup 1.0000x reference)
//
#include <hip/hip_runtime.h>
#include <hip/hip_bf16.h>

// Problem constants
#define AG 8
#define BT 2048
#define RT (AG*BT)      // 16384 rows
#define NNET 4
#define D0 128
#define H1 1024
#define H2 1024
#define H3 512

// counts[n] ~ Binomial(16384,1/4) = 4096 +/- 55; 5120 = +18 sigma.
// BM=256 -> grid x = 5120/256 = 20.
#define XBLK 20

typedef __attribute__((ext_vector_type(8))) short short8;
typedef __attribute__((ext_vector_type(4))) float f32x4;

__device__ __forceinline__ unsigned short f2bf(float f){
  unsigned int x = __float_as_uint(f);
  x += 0x7fff + ((x >> 16) & 1);   // RNE
  return (unsigned short)(x >> 16);
}

__device__ __forceinline__ void gload_lds16(const void* g, void* l){
  __builtin_amdgcn_global_load_lds(
      (const __attribute__((address_space(1))) unsigned int*)g,
      (__attribute__((address_space(3))) unsigned int*)l, 16, 0, 0);
}

__device__ __forceinline__ int bucket_off(const int* counts, int n){
  int s = 0;
  #pragma unroll
  for (int i = 0; i < NNET-1; i++) if (i < n) s += counts[i];
  return s;
}

__global__ void k_init(int* counts){
  if (threadIdx.x < NNET) counts[threadIdx.x] = 0;
}

// Hierarchical compaction: LDS-local rank + one global atomicAdd per (block,net).
__global__ __launch_bounds__(256) void k_compact(const int* __restrict__ seps,
                          int* __restrict__ counts, int* __restrict__ rowlist){
  __shared__ int lcount[NNET];
  __shared__ int lbase[NNET];
  int t = blockIdx.x * 256 + threadIdx.x;
  if (threadIdx.x < NNET) lcount[threadIdx.x] = 0;
  __syncthreads();
  int a = t >> 11, b = t & (BT-1);
  int n = seps[b*AG + a];               // seps_indices is [B,A]
  int lrank = atomicAdd(&lcount[n], 1);
  __syncthreads();
  if (threadIdx.x < NNET)
    lbase[threadIdx.x] = atomicAdd(&counts[threadIdx.x], lcount[threadIdx.x]);
  __syncthreads();
  rowlist[n*RT + lbase[n] + lrank] = t;
}

// W[n][K][NOUT] f32 -> WT[n][NOUT][K] bf16
template<int K, int NOUT>
__global__ __launch_bounds__(256) void k_transpose(const float* __restrict__ W,
                                                   unsigned short* __restrict__ WT){
  __shared__ float tile[32][33];
  int n = blockIdx.z;
  int k0 = blockIdx.x*32, o0 = blockIdx.y*32;
  const float* Wn = W + (size_t)n*K*NOUT;
  unsigned short* WTn = WT + (size_t)n*NOUT*K;
  int tx = threadIdx.x & 31, ty0 = threadIdx.x >> 5;
  #pragma unroll
  for (int r = 0; r < 32; r += 8)
    tile[ty0 + r][tx] = Wn[(size_t)(k0 + ty0 + r)*NOUT + o0 + tx];
  __syncthreads();
  #pragma unroll
  for (int r = 0; r < 32; r += 8)
    WTn[(size_t)(o0 + ty0 + r)*K + k0 + tx] = f2bf(tile[tx][ty0 + r]);
}

// gather fp32 input rows -> compacted bf16 X0h[RT][D0]
__global__ __launch_bounds__(256) void k_gather0(const float* __restrict__ X,
                          const int* __restrict__ counts,
                          const int* __restrict__ rowlist, unsigned short* __restrict__ X0h){
  int n = blockIdx.y;
  int cnt = counts[n];
  int i = blockIdx.x*16 + (threadIdx.x >> 4);
  if (i >= cnt) return;
  int off = bucket_off(counts, n);
  int orig = rowlist[n*RT + i];
  int c = (threadIdx.x & 15) * 8;
  const float* src = X + (size_t)orig*D0 + c;
  float4 v0 = *(const float4*)src, v1 = *(const float4*)(src+4);
  ushort4 u0, u1;
  u0.x=f2bf(v0.x); u0.y=f2bf(v0.y); u0.z=f2bf(v0.z); u0.w=f2bf(v0.w);
  u1.x=f2bf(v1.x); u1.y=f2bf(v1.y); u1.z=f2bf(v1.z); u1.w=f2bf(v1.w);
  unsigned short* dst = X0h + (size_t)(off + i)*D0 + c;
  *(ushort4*)dst = u0; *(ushort4*)(dst+4) = u1;
}

// MFMA GEMM: C[rows,NOUT] = X[rows,K] * WT[NOUT,K]^T + bias, one network bucket.
// 256x128 tile (R16 diagnosis: invariant 65us == staging-BW identity; 128^2
// stages 1/64 B/FLOP -> 640 TF cap at the measured ~10 TB/s L2->LDS rate;
// 256x128 stages (256+128)/(2*256*128) = 1/85 B/FLOP -> ~850 TF cap).
// BK=32, 4 waves (2x2), wave-tile 128x64 (MF=8 x NF=4 = 32 MFMA/step).
// R14-proven skeleton unchanged: single-barrier 2-buffer de-pinned pipeline
//   [vmcnt(0) | lgkmcnt(0) | barrier | sched_barrier | stage ks+1 -> b^1 |
//    ds_reads + MFMA from b]   (stage = 4 A-issues + 2 B-issues / thread)
// MFMA as mfma(bv, av, acc): lane's 4 acc regs = 4 consecutive output cols.
// 16B-slot XOR swizzle (slot ^= (row>>1)&3) on BOTH global source and ds_read.
// __launch_bounds__(256,2): acc 128 VGPR + frags -> ~2 waves/SIMD; LDS 49KB.
template<int K, int NOUT, int RELU, int SCATTER>
__global__ __launch_bounds__(256, 2) void k_mlp(
    const unsigned short* __restrict__ X,   // compacted bf16 [RT, K]
    const unsigned short* __restrict__ WT,  // [N, NOUT, K] bf16
    const float* __restrict__ Bias,         // [N, NOUT] f32
    const int* __restrict__ counts,
    const int* __restrict__ rowlist,
    unsigned short* __restrict__ Yh,        // compacted bf16 out
    float* __restrict__ Yf)                 // scatter f32 out
{
  constexpr int T = K / 32;                 // K-steps
  const int n = blockIdx.z;
  const int cnt = counts[n];
  const int i0 = blockIdx.x * 256;
  if (i0 >= cnt) return;
  const int off = bucket_off(counts, n);
  const int bn = blockIdx.y * 128;

  __shared__ __align__(16) unsigned short As[2][256*32];  // 16KB per buf
  __shared__ __align__(16) unsigned short Bs[2][128*32];  // 8KB per buf
  __shared__ int rs[256];

  const int t = threadIdx.x, lane = t & 63, wave = t >> 6;
  const int wm = wave >> 1, wn = wave & 1;
  const int lr = lane & 15, g = lane >> 4;

  if (SCATTER) rs[t] = rowlist[n*RT + min(i0 + t, cnt-1)];

  // staging: A tile 256x32 = 1024 16B-slots (4 issues/thread); B 128x32 = 512
  // slots (2 issues/thread). slot s -> row = s>>2, phys slot = s&3; global
  // source uses inverse-swizzled logical slot (rule #21).
  const unsigned short* pA[4]; const unsigned short* pB[2];
  unsigned int loffA[4], loffB[2];
  const unsigned short* WTn = WT + (size_t)n * NOUT * K;
  #pragma unroll
  for (int j = 0; j < 4; j++){
    int s = j*256 + t, r = s >> 2;
    int ls = (s & 3) ^ ((r >> 1) & 3);
    pA[j] = X + (size_t)(off + min(i0 + r, cnt-1))*K + ls*8;
    loffA[j] = (unsigned)s * 8;
  }
  #pragma unroll
  for (int j = 0; j < 2; j++){
    int s = j*256 + t, r = s >> 2;
    int ls = (s & 3) ^ ((r >> 1) & 3);
    pB[j] = WTn + (size_t)(bn + r)*K + ls*8;
    loffB[j] = (unsigned)s * 8;
  }

  // fragment ds_read offsets (swizzled)
  int aoff[8], boff[4];
  #pragma unroll
  for (int i = 0; i < 8; i++){
    int ra = wm*128 + i*16 + lr;
    aoff[i] = ra*32 + (g ^ ((ra>>1)&3))*8;
  }
  #pragma unroll
  for (int i = 0; i < 4; i++){
    int rb = wn*64 + i*16 + lr;
    boff[i] = rb*32 + (g ^ ((rb>>1)&3))*8;
  }

  __syncthreads();   // rs visible; clean vmcnt ledger

  // prologue: stage K-step 0 into buffer 0 (6 issues/thread in flight)
  #pragma unroll
  for (int j = 0; j < 4; j++){ gload_lds16(pA[j], &As[0][loffA[j]]); pA[j] += 32; }
  #pragma unroll
  for (int j = 0; j < 2; j++){ gload_lds16(pB[j], &Bs[0][loffB[j]]); pB[j] += 32; }

  f32x4 acc[8][4] = {};
  for (int ks = 0; ks < T; ++ks){
    const int b = ks & 1;
    asm volatile("s_waitcnt vmcnt(0)" ::: "memory");    // buf b's set landed
    asm volatile("s_waitcnt lgkmcnt(0)" ::: "memory");  // my ks-1 reads done
    __builtin_amdgcn_s_barrier();             // all waves: landed + done reading
    __builtin_amdgcn_sched_barrier(0);        // no hoisting above the barrier

    if (ks + 1 < T){                          // stage ks+1 into b^1 (last read ks-1)
      #pragma unroll
      for (int j = 0; j < 4; j++){ gload_lds16(pA[j], &As[b^1][loffA[j]]); pA[j] += 32; }
      #pragma unroll
      for (int j = 0; j < 2; j++){ gload_lds16(pB[j], &Bs[b^1][loffB[j]]); pB[j] += 32; }
    }

    short8 av[8], bv[4];
    #pragma unroll
    for (int i = 0; i < 8; i++) av[i] = *(const short8*)&As[b][aoff[i]];
    #pragma unroll
    for (int i = 0; i < 4; i++) bv[i] = *(const short8*)&Bs[b][boff[i]];
    // De-pinned: compiler interleaves ds_reads and MFMAs with incremental lgkmcnt.
    #pragma unroll
    for (int mi = 0; mi < 8; mi++)
      #pragma unroll
      for (int ni = 0; ni < 4; ni++)
        acc[mi][ni] = __builtin_amdgcn_mfma_f32_16x16x32_bf16(bv[ni], av[mi], acc[mi][ni], 0, 0, 0);
  }

  // epilogue (swapped field-map): lane's reg i = output col (ni*16 + g*4 + i),
  // output row = wm*128 + mi*16 + lr.  Bias as float4, stores float4/ushort4.
  f32x4 bias4[4];
  #pragma unroll
  for (int ni = 0; ni < 4; ni++)
    bias4[ni] = *(const f32x4*)&Bias[n*NOUT + bn + wn*64 + ni*16 + (g<<2)];

  #pragma unroll
  for (int mi = 0; mi < 8; mi++){
    int rloc = wm*128 + mi*16 + lr;
    int grow = i0 + rloc;
    if (grow < cnt){
      #pragma unroll
      for (int ni = 0; ni < 4; ni++){
        float o[4];
        #pragma unroll
        for (int i = 0; i < 4; i++){
          float v = acc[mi][ni][i] + bias4[ni][i];
          if (RELU) v = fmaxf(v, 0.f);
          o[i] = v;
        }
        int cb = bn + wn*64 + ni*16 + (g<<2);
        if (SCATTER){
          *(float4*)&Yf[(size_t)rs[rloc]*NOUT + cb] = make_float4(o[0],o[1],o[2],o[3]);
        } else {
          ushort4 u;
          u.x=f2bf(o[0]); u.y=f2bf(o[1]); u.z=f2bf(o[2]); u.w=f2bf(o[3]);
          *(ushort4*)&Yh[(size_t)(off + grow)*NOUT + cb] = u;
        }
      }
    }
  }
}

extern "C" void kernel_launch(void* const* d_in, const int* in_sizes, int n_in,
                              void* d_out, int out_size, void* d_ws, size_t ws_size,
                              hipStream_t stream) {
  const float* inputs = (const float*)d_in[0];
  const int*   seps   = (const int*)  d_in[1];
  const float* W0     = (const float*)d_in[2];
  const float* b0     = (const float*)d_in[3];
  const float* W1     = (const float*)d_in[4];
  const float* b1     = (const float*)d_in[5];
  const float* W2     = (const float*)d_in[6];
  const float* b2     = (const float*)d_in[7];
  float* out = (float*)d_out;

  // ws layout (78 MiB):
  // 0: counts | 4K: rowlist(256K) | 1M: WT0(1M) | 2M: WT1(8M) | 10M: WT2(4M)
  // 14M: h1(32M) | 46M: h2(32M), X0h(4M) overlaps h2 start (disjoint lifetimes)
  char* ws = (char*)d_ws;
  int* counts  = (int*)ws;
  int* rowlist = (int*)(ws + 4096);
  const size_t MB = 1u << 20;
  unsigned short* WT0 = (unsigned short*)(ws + 1*MB);
  unsigned short* WT1 = (unsigned short*)(ws + 2*MB);
  unsigned short* WT2 = (unsigned short*)(ws + 10*MB);
  unsigned short* h1  = (unsigned short*)(ws + 14*MB);
  unsigned short* h2  = (unsigned short*)(ws + 46*MB);
  unsigned short* X0h = (unsigned short*)(ws + 46*MB);  // dead before h2 written

  k_init   <<<1, 64, 0, stream>>>(counts);
  k_compact<<<RT/256, 256, 0, stream>>>(seps, counts, rowlist);

  k_transpose<D0, H1><<<dim3(D0/32, H1/32, NNET), 256, 0, stream>>>(W0, WT0);
  k_transpose<H1, H2><<<dim3(H1/32, H2/32, NNET), 256, 0, stream>>>(W1, WT1);
  k_transpose<H2, H3><<<dim3(H2/32, H3/32, NNET), 256, 0, stream>>>(W2, WT2);
  k_gather0<<<dim3(RT/16, NNET), 256, 0, stream>>>(inputs, counts, rowlist, X0h);

  // Layer 0: K=128
  k_mlp<D0, H1, 1, 0><<<dim3(XBLK, H1/128, NNET), 256, 0, stream>>>(
      X0h, WT0, b0, counts, rowlist, h1, nullptr);
  // Layer 1: K=1024
  k_mlp<H1, H2, 1, 0><<<dim3(XBLK, H2/128, NNET), 256, 0, stream>>>(
      h1, WT1, b1, counts, rowlist, h2, nullptr);
  // Layer 2: K=1024, N=512, scatter f32
  k_mlp<H2, H3, 0, 1><<<dim3(XBLK, H3/128, NNET), 256, 0, stream>>>(
      h2, WT2, b2, counts, rowlist, nullptr, out);
}

// Round 18
// 157.951 us; speedup vs baseline: 1.1164x; 1.1164x over previous
//
#include <hip/hip_runtime.h>
#include <hip/hip_bf16.h>

// Problem constants
#define AG 8
#define BT 2048
#define RT (AG*BT)      // 16384 rows
#define NNET 4
#define D0 128
#define H1 1024
#define H2 1024
#define H3 512

// counts[n] ~ Binomial(16384,1/4) = 4096 +/- 55; 5120 = +18 sigma.
#define XBLK 40         // 128-row tiles (L0/L2)
#define XBLK8 20        // 256-row tiles (L1): ~16 real blocks + 4 instant-exit duds

typedef __attribute__((ext_vector_type(8))) short short8;
typedef __attribute__((ext_vector_type(4))) float f32x4;

__device__ __forceinline__ unsigned short f2bf(float f){
  unsigned int x = __float_as_uint(f);
  x += 0x7fff + ((x >> 16) & 1);   // RNE
  return (unsigned short)(x >> 16);
}

template<int N> __device__ __forceinline__ void vmw(){
  if constexpr (N==8)      asm volatile("s_waitcnt vmcnt(8)" ::: "memory");
  else if constexpr (N==4) asm volatile("s_waitcnt vmcnt(4)" ::: "memory");
  else                     asm volatile("s_waitcnt vmcnt(0)" ::: "memory");
}

__device__ __forceinline__ void gload_lds16(const void* g, void* l){
  __builtin_amdgcn_global_load_lds(
      (const __attribute__((address_space(1))) unsigned int*)g,
      (__attribute__((address_space(3))) unsigned int*)l, 16, 0, 0);
}

__device__ __forceinline__ int bucket_off(const int* counts, int n){
  int s = 0;
  #pragma unroll
  for (int i = 0; i < NNET-1; i++) if (i < n) s += counts[i];
  return s;
}

__global__ void k_init(int* counts){
  if (threadIdx.x < NNET) counts[threadIdx.x] = 0;
}

// Hierarchical compaction: LDS-local rank + one global atomicAdd per (block,net).
__global__ __launch_bounds__(256) void k_compact(const int* __restrict__ seps,
                          int* __restrict__ counts, int* __restrict__ rowlist){
  __shared__ int lcount[NNET];
  __shared__ int lbase[NNET];
  int t = blockIdx.x * 256 + threadIdx.x;
  if (threadIdx.x < NNET) lcount[threadIdx.x] = 0;
  __syncthreads();
  int a = t >> 11, b = t & (BT-1);
  int n = seps[b*AG + a];               // seps_indices is [B,A]
  int lrank = atomicAdd(&lcount[n], 1);
  __syncthreads();
  if (threadIdx.x < NNET)
    lbase[threadIdx.x] = atomicAdd(&counts[threadIdx.x], lcount[threadIdx.x]);
  __syncthreads();
  rowlist[n*RT + lbase[n] + lrank] = t;
}

// W[n][K][NOUT] f32 -> WT[n][NOUT][K] bf16
template<int K, int NOUT>
__global__ __launch_bounds__(256) void k_transpose(const float* __restrict__ W,
                                                   unsigned short* __restrict__ WT){
  __shared__ float tile[32][33];
  int n = blockIdx.z;
  int k0 = blockIdx.x*32, o0 = blockIdx.y*32;
  const float* Wn = W + (size_t)n*K*NOUT;
  unsigned short* WTn = WT + (size_t)n*NOUT*K;
  int tx = threadIdx.x & 31, ty0 = threadIdx.x >> 5;
  #pragma unroll
  for (int r = 0; r < 32; r += 8)
    tile[ty0 + r][tx] = Wn[(size_t)(k0 + ty0 + r)*NOUT + o0 + tx];
  __syncthreads();
  #pragma unroll
  for (int r = 0; r < 32; r += 8)
    WTn[(size_t)(o0 + ty0 + r)*K + k0 + tx] = f2bf(tile[tx][ty0 + r]);
}

// gather fp32 input rows -> compacted bf16 X0h[RT][D0]
__global__ __launch_bounds__(256) void k_gather0(const float* __restrict__ X,
                          const int* __restrict__ counts,
                          const int* __restrict__ rowlist, unsigned short* __restrict__ X0h){
  int n = blockIdx.y;
  int cnt = counts[n];
  int i = blockIdx.x*16 + (threadIdx.x >> 4);
  if (i >= cnt) return;
  int off = bucket_off(counts, n);
  int orig = rowlist[n*RT + i];
  int c = (threadIdx.x & 15) * 8;
  const float* src = X + (size_t)orig*D0 + c;
  float4 v0 = *(const float4*)src, v1 = *(const float4*)(src+4);
  ushort4 u0, u1;
  u0.x=f2bf(v0.x); u0.y=f2bf(v0.y); u0.z=f2bf(v0.z); u0.w=f2bf(v0.w);
  u1.x=f2bf(v1.x); u1.y=f2bf(v1.y); u1.z=f2bf(v1.z); u1.w=f2bf(v1.w);
  unsigned short* dst = X0h + (size_t)(off + i)*D0 + c;
  *(ushort4*)dst = u0; *(ushort4*)(dst+4) = u1;
}

// ===== R10-proven 128x128 4-wave kernel (L0 / L2) ====================
// 3 LDS buffers, counted vmcnt, single-pass; PIN=0 de-pinned / PIN=1 control.
template<int K, int NOUT, int RELU, int SCATTER, int PIN>
__global__ __launch_bounds__(256, 2) void k_mlp(
    const unsigned short* __restrict__ X,
    const unsigned short* __restrict__ WT,
    const float* __restrict__ Bias,
    const int* __restrict__ counts,
    const int* __restrict__ rowlist,
    unsigned short* __restrict__ Yh,
    float* __restrict__ Yf)
{
  constexpr int T = K / 32;
  const int n = blockIdx.z;
  const int cnt = counts[n];
  const int i0 = blockIdx.x * 128;
  if (i0 >= cnt) return;
  const int off = bucket_off(counts, n);
  const int bn = blockIdx.y * 128;

  __shared__ __align__(16) unsigned short As[3][128*32];
  __shared__ __align__(16) unsigned short Bs[3][128*32];
  __shared__ int rs[128];

  const int t = threadIdx.x, lane = t & 63, wave = t >> 6;
  const int wm = wave >> 1, wn = wave & 1;
  const int lr = lane & 15, g = lane >> 4;

  if (SCATTER && t < 128) rs[t] = rowlist[n*RT + min(i0 + t, cnt-1)];

  const unsigned short* pA[2]; const unsigned short* pB[2];
  unsigned int ldsoff[2];
  const unsigned short* WTn = WT + (size_t)n * NOUT * K;
  #pragma unroll
  for (int j = 0; j < 2; j++){
    int r  = (j*4 + wave)*16 + (lane >> 2);
    int ps = lane & 3;
    int ls = ps ^ ((r >> 1) & 3);
    int rA = min(i0 + r, cnt-1);
    pA[j] = X   + (size_t)(off + rA)*K + ls*8;
    pB[j] = WTn + (size_t)(bn  + r )*K + ls*8;
    ldsoff[j] = (unsigned)(j*4 + wave) * 512;
  }

  int aoff[4], boff[4];
  #pragma unroll
  for (int i = 0; i < 4; i++){
    int ra = wm*64 + i*16 + lr;
    aoff[i] = ra*32 + (g ^ ((ra>>1)&3))*8;
    int rb = wn*64 + i*16 + lr;
    boff[i] = rb*32 + (g ^ ((rb>>1)&3))*8;
  }

  __syncthreads();

  #pragma unroll
  for (int s = 0; s < 3; ++s){
    #pragma unroll
    for (int j = 0; j < 2; j++){
      gload_lds16(pA[j], &As[s][ldsoff[j]]);
      gload_lds16(pB[j], &Bs[s][ldsoff[j]]);
      pA[j] += 32; pB[j] += 32;
    }
  }

  f32x4 acc[4][4] = {};
  int b = 0;
  for (int ks = 0; ks < T; ++ks){
    if (ks < T-2)       vmw<8>();
    else if (ks == T-2) vmw<4>();
    else                vmw<0>();
    __builtin_amdgcn_s_barrier();

    short8 av[4], bv[4];
    #pragma unroll
    for (int i = 0; i < 4; i++) av[i] = *(const short8*)&As[b][aoff[i]];
    #pragma unroll
    for (int i = 0; i < 4; i++) bv[i] = *(const short8*)&Bs[b][boff[i]];

    if constexpr (PIN){
      asm volatile("s_waitcnt lgkmcnt(0)" ::: "memory");
      __builtin_amdgcn_sched_barrier(0);
      __builtin_amdgcn_s_barrier();
      if (ks + 3 < T){
        #pragma unroll
        for (int j = 0; j < 2; j++){
          gload_lds16(pA[j], &As[b][ldsoff[j]]);
          gload_lds16(pB[j], &Bs[b][ldsoff[j]]);
          pA[j] += 32; pB[j] += 32;
        }
      }
      __builtin_amdgcn_s_setprio(1);
      #pragma unroll
      for (int mi = 0; mi < 4; mi++)
        #pragma unroll
        for (int ni = 0; ni < 4; ni++)
          acc[mi][ni] = __builtin_amdgcn_mfma_f32_16x16x32_bf16(bv[ni], av[mi], acc[mi][ni], 0, 0, 0);
      __builtin_amdgcn_s_setprio(0);
    } else {
      #pragma unroll
      for (int mi = 0; mi < 4; mi++)
        #pragma unroll
        for (int ni = 0; ni < 4; ni++)
          acc[mi][ni] = __builtin_amdgcn_mfma_f32_16x16x32_bf16(bv[ni], av[mi], acc[mi][ni], 0, 0, 0);
      asm volatile("s_waitcnt lgkmcnt(0)" ::: "memory");
      __builtin_amdgcn_s_barrier();
      if (ks + 3 < T){
        #pragma unroll
        for (int j = 0; j < 2; j++){
          gload_lds16(pA[j], &As[b][ldsoff[j]]);
          gload_lds16(pB[j], &Bs[b][ldsoff[j]]);
          pA[j] += 32; pB[j] += 32;
        }
      }
    }
    b = (b == 2) ? 0 : b + 1;
  }

  f32x4 bias4[4];
  #pragma unroll
  for (int ni = 0; ni < 4; ni++)
    bias4[ni] = *(const f32x4*)&Bias[n*NOUT + bn + wn*64 + ni*16 + (g<<2)];

  #pragma unroll
  for (int mi = 0; mi < 4; mi++){
    int rloc = wm*64 + mi*16 + lr;
    int grow = i0 + rloc;
    if (grow < cnt){
      #pragma unroll
      for (int ni = 0; ni < 4; ni++){
        float o[4];
        #pragma unroll
        for (int i = 0; i < 4; i++){
          float v = acc[mi][ni][i] + bias4[ni][i];
          if (RELU) v = fmaxf(v, 0.f);
          o[i] = v;
        }
        int cb = bn + wn*64 + ni*16 + (g<<2);
        if (SCATTER){
          *(float4*)&Yf[(size_t)rs[rloc]*NOUT + cb] = make_float4(o[0],o[1],o[2],o[3]);
        } else {
          ushort4 u;
          u.x=f2bf(o[0]); u.y=f2bf(o[1]); u.z=f2bf(o[2]); u.w=f2bf(o[3]);
          *(ushort4*)&Yh[(size_t)(off + grow)*NOUT + cb] = u;
        }
      }
    }
  }
}

// ===== NEW: 8-wave 256x256 two-phase counted pipeline (L1) ===========
// 512 thr (2M x 4N waves), wave-tile 128x64 (MF=8 x NF=4), BK=32.
// 3 LDS buffers (96KB -> 1 block/CU; effective grid = 256 blocks = 1/CU,
// dud blocks exit instantly). 2-step lookahead: step s stages s+2 into
// buf (s+2)%3 == (s-1)%3 (freed by p0's lgkm+barrier). Counted vmcnt(4)
// once per step (in-flight at p0 = steps {s,s+1} x 4 loads; drain s's 4);
// never 0 until the tail -> ~2 steps (~800cy) of load-latency cover.
// Phase p0: [vmw | lgkm0 | barrier | schedbar | stage A(s+2) | read av0-3,
// bv0-3 | 16 MFMA (setprio)]. Phase p1: [barrier | stage B(s+2) | read
// av4-7 | 16 MFMA (setprio)]. De-pinned reads->MFMA (compiler incremental
// lgkmcnt). Swizzle identical to proven 4-wave kernel.
template<int K, int NOUT, int RELU>
__global__ __launch_bounds__(512, 1) void k_mlp8(
    const unsigned short* __restrict__ X,   // compacted bf16 [RT, K]
    const unsigned short* __restrict__ WT,  // [N, NOUT, K] bf16
    const float* __restrict__ Bias,         // [N, NOUT] f32
    const int* __restrict__ counts,
    unsigned short* __restrict__ Yh)        // compacted bf16 out
{
  constexpr int T = K / 32;                 // K-steps (32 for L1)
  const int n = blockIdx.z;
  const int cnt = counts[n];
  const int i0 = blockIdx.x * 256;
  if (i0 >= cnt) return;                    // dud blocks exit instantly
  const int off = bucket_off(counts, n);
  const int bn = blockIdx.y * 256;

  __shared__ __align__(16) unsigned short As[3][256*32];  // 16KB each
  __shared__ __align__(16) unsigned short Bs[3][256*32];  // 16KB each

  const int t = threadIdx.x, lane = t & 63;
  const int wave = t >> 6;                  // 0..7
  const int wm = wave >> 2, wn = wave & 3;  // 2M x 4N
  const int lr = lane & 15, g = lane >> 4;

  // staging: 256x32 tile = 1024 16B-slots; 512 thr -> 2 issues each.
  // slot s = j*512 + t: row = s>>2, phys slot = s&3; global src uses the
  // inverse-swizzled logical slot (rule #21). Per-wave slots contiguous ->
  // wave-uniform LDS base + lane*16 (gload_lds requirement).
  const unsigned short* pA[2]; const unsigned short* pB[2];
  unsigned int loffA[2], loffB[2];
  const unsigned short* WTn = WT + (size_t)n * NOUT * K;
  #pragma unroll
  for (int j = 0; j < 2; j++){
    int s = j*512 + t, r = s >> 2;
    int ls = (s & 3) ^ ((r >> 1) & 3);
    pA[j] = X   + (size_t)(off + min(i0 + r, cnt-1))*K + ls*8;
    pB[j] = WTn + (size_t)(bn + r)*K + ls*8;
    loffA[j] = (unsigned)s * 8;
    loffB[j] = (unsigned)s * 8;
  }

  // fragment ds_read offsets (swizzled)
  int aoff[8], boff[4];
  #pragma unroll
  for (int i = 0; i < 8; i++){
    int ra = wm*128 + i*16 + lr;
    aoff[i] = ra*32 + (g ^ ((ra>>1)&3))*8;
  }
  #pragma unroll
  for (int i = 0; i < 4; i++){
    int rb = wn*64 + i*16 + lr;
    boff[i] = rb*32 + (g ^ ((rb>>1)&3))*8;
  }

  __syncthreads();   // clean vmcnt ledger

  // prologue: stage steps 0,1 into bufs 0,1 (8 loads/thread in flight)
  #pragma unroll
  for (int s = 0; s < 2; ++s){
    #pragma unroll
    for (int j = 0; j < 2; j++){
      gload_lds16(pA[j], &As[s][loffA[j]]);
      gload_lds16(pB[j], &Bs[s][loffB[j]]);
      pA[j] += 32; pB[j] += 32;
    }
  }

  f32x4 acc[8][4] = {};
  short8 bv[4];
  int b = 0, d = 2;                         // read buf (s%3), stage buf ((s+2)%3)
  for (int s = 0; s < T; ++s){
    // ---- phase 0: gate + quadrant mi0-3
    if (s < T-1) vmw<4>(); else vmw<0>();   // step-s loads landed (mine)
    asm volatile("s_waitcnt lgkmcnt(0)" ::: "memory");  // my s-1 reads done
    __builtin_amdgcn_s_barrier();           // all waves: landed + done reading
    __builtin_amdgcn_sched_barrier(0);

    if (s + 2 < T){                         // stage A(s+2) into buf d
      #pragma unroll
      for (int j = 0; j < 2; j++){ gload_lds16(pA[j], &As[d][loffA[j]]); pA[j] += 32; }
    }
    {
      short8 av[4];
      #pragma unroll
      for (int i = 0; i < 4; i++) av[i] = *(const short8*)&As[b][aoff[i]];
      #pragma unroll
      for (int i = 0; i < 4; i++) bv[i] = *(const short8*)&Bs[b][boff[i]];
      __builtin_amdgcn_s_setprio(1);
      #pragma unroll
      for (int mi = 0; mi < 4; mi++)
        #pragma unroll
        for (int ni = 0; ni < 4; ni++)
          acc[mi][ni] = __builtin_amdgcn_mfma_f32_16x16x32_bf16(bv[ni], av[mi], acc[mi][ni], 0, 0, 0);
      __builtin_amdgcn_s_setprio(0);
    }

    // ---- phase 1: quadrant mi4-7 (bv reused)
    __builtin_amdgcn_s_barrier();           // wave stagger (no data hazard)
    if (s + 2 < T){                         // stage B(s+2) into buf d
      #pragma unroll
      for (int j = 0; j < 2; j++){ gload_lds16(pB[j], &Bs[d][loffB[j]]); pB[j] += 32; }
    }
    {
      short8 av[4];
      #pragma unroll
      for (int i = 0; i < 4; i++) av[i] = *(const short8*)&As[b][aoff[4+i]];
      __builtin_amdgcn_s_setprio(1);
      #pragma unroll
      for (int mi = 0; mi < 4; mi++)
        #pragma unroll
        for (int ni = 0; ni < 4; ni++)
          acc[4+mi][ni] = __builtin_amdgcn_mfma_f32_16x16x32_bf16(bv[ni], av[mi], acc[4+mi][ni], 0, 0, 0);
      __builtin_amdgcn_s_setprio(0);
    }

    b = (b == 2) ? 0 : b + 1;
    d = (d == 2) ? 0 : d + 1;
  }

  // epilogue (swapped field-map): lane reg i = col (ni*16 + g*4 + i),
  // row = wm*128 + mi*16 + lr.
  f32x4 bias4[4];
  #pragma unroll
  for (int ni = 0; ni < 4; ni++)
    bias4[ni] = *(const f32x4*)&Bias[n*NOUT + bn + wn*64 + ni*16 + (g<<2)];

  #pragma unroll
  for (int mi = 0; mi < 8; mi++){
    int rloc = wm*128 + mi*16 + lr;
    int grow = i0 + rloc;
    if (grow < cnt){
      #pragma unroll
      for (int ni = 0; ni < 4; ni++){
        float o[4];
        #pragma unroll
        for (int i = 0; i < 4; i++){
          float v = acc[mi][ni][i] + bias4[ni][i];
          if (RELU) v = fmaxf(v, 0.f);
          o[i] = v;
        }
        int cb = bn + wn*64 + ni*16 + (g<<2);
        ushort4 u;
        u.x=f2bf(o[0]); u.y=f2bf(o[1]); u.z=f2bf(o[2]); u.w=f2bf(o[3]);
        *(ushort4*)&Yh[(size_t)(off + grow)*NOUT + cb] = u;
      }
    }
  }
}

extern "C" void kernel_launch(void* const* d_in, const int* in_sizes, int n_in,
                              void* d_out, int out_size, void* d_ws, size_t ws_size,
                              hipStream_t stream) {
  const float* inputs = (const float*)d_in[0];
  const int*   seps   = (const int*)  d_in[1];
  const float* W0     = (const float*)d_in[2];
  const float* b0     = (const float*)d_in[3];
  const float* W1     = (const float*)d_in[4];
  const float* b1     = (const float*)d_in[5];
  const float* W2     = (const float*)d_in[6];
  const float* b2     = (const float*)d_in[7];
  float* out = (float*)d_out;

  // ws layout (78 MiB):
  // 0: counts | 4K: rowlist(256K) | 1M: WT0(1M) | 2M: WT1(8M) | 10M: WT2(4M)
  // 14M: h1(32M) | 46M: h2(32M), X0h(4M) overlaps h2 start (disjoint lifetimes)
  char* ws = (char*)d_ws;
  int* counts  = (int*)ws;
  int* rowlist = (int*)(ws + 4096);
  const size_t MB = 1u << 20;
  unsigned short* WT0 = (unsigned short*)(ws + 1*MB);
  unsigned short* WT1 = (unsigned short*)(ws + 2*MB);
  unsigned short* WT2 = (unsigned short*)(ws + 10*MB);
  unsigned short* h1  = (unsigned short*)(ws + 14*MB);
  unsigned short* h2  = (unsigned short*)(ws + 46*MB);
  unsigned short* X0h = (unsigned short*)(ws + 46*MB);  // dead before h2 written

  k_init   <<<1, 64, 0, stream>>>(counts);
  k_compact<<<RT/256, 256, 0, stream>>>(seps, counts, rowlist);

  k_transpose<D0, H1><<<dim3(D0/32, H1/32, NNET), 256, 0, stream>>>(W0, WT0);
  k_transpose<H1, H2><<<dim3(H1/32, H2/32, NNET), 256, 0, stream>>>(W1, WT1);
  k_transpose<H2, H3><<<dim3(H2/32, H3/32, NNET), 256, 0, stream>>>(W2, WT2);
  k_gather0<<<dim3(RT/16, NNET), 256, 0, stream>>>(inputs, counts, rowlist, X0h);

  // Layer 0: K=128, R10-proven 128^2 kernel (PIN=0)
  k_mlp<D0, H1, 1, 0, 0><<<dim3(XBLK, H1/128, NNET), 256, 0, stream>>>(
      X0h, WT0, b0, counts, rowlist, h1, nullptr);
  // Layer 1: K=1024, NEW 8-wave 256^2 two-phase pipeline
  k_mlp8<H1, H2, 1><<<dim3(XBLK8, H2/256, NNET), 512, 0, stream>>>(
      h1, WT1, b1, counts, h2);
  // Layer 2: K=1024, N=512, R10-proven kernel (PIN=1), scatter f32
  k_mlp<H2, H3, 0, 1, 1><<<dim3(XBLK, H3/128, NNET), 256, 0, stream>>>(
      h2, WT2, b2, counts, rowlist, nullptr, out);
}